// Round 7
// baseline (69.562 us; speedup 1.0000x reference)
//
#include <hip/hip_runtime.h>
#include <math.h>

#define NPTS 262144
#define B_KB 4.71238898038469f      /* 1.5*pi */
#define B_KB2 22.2066099025f        /* B_KB^2 */
#define PI_F 3.14159265358979f
#define INV_2PI 0.15915494309f      /* 1/(2*pi) */
#define TWO_PI_OVER_N 0.01227184630309f /* 2*pi/512 */
#define NCOL 520                    /* padded row stride: 512 + 8 dup cols */
#define NBKT 4096                   /* 64x64 tiles of 8x8 grid cells */

__device__ __forceinline__ float i0f_dev(float x) {
    float ax = fabsf(x);
    if (ax < 3.75f) {
        float t = ax / 3.75f; t *= t;
        return 1.0f + t*(3.5156229f + t*(3.0899424f + t*(1.2067492f +
               t*(0.2659732f + t*(0.0360768f + t*0.0045813f)))));
    } else {
        float t = 3.75f / ax;
        float p = 0.39894228f + t*(0.01328592f + t*(0.00225319f + t*(-0.00157565f +
                  t*(0.00916281f + t*(-0.02057706f + t*(0.02635537f +
                  t*(-0.01647633f + t*0.00392377f)))))));
        return expf(ax) * p / sqrtf(ax);
    }
}

// Kaiser-Bessel window via raw v_exp/v_rcp: sinh(B*a)/(pi*a), a=sqrt(16-t^2)
__device__ __forceinline__ float phi_win(float t) {
    float s = 16.0f - t * t;
    if (s <= 0.0f) return 0.0f;
    float a = sqrtf(s);
    float ez = __expf(B_KB * a);
    return (ez - __builtin_amdgcn_rcpf(ez)) * INV_2PI * __builtin_amdgcn_rcpf(a);
}

__device__ __forceinline__ int bucket_of(float2 xv) {
    int r0 = (((int)ceilf(xv.x * 512.0f)) - 4 + 768) & 511;
    int c0 = (((int)ceilf(xv.y * 512.0f)) - 4 + 768) & 511;
    return ((r0 >> 3) << 6) | (c0 >> 3);
}

// ---- Fused deconvolution + row FFT (rows with nonzero spectrum only). ----
// Also zeroes the sort histogram (runs first in the graph).
__global__ void rowfft_build(const float* __restrict__ fr,
                             const float* __restrict__ fi,
                             float2* __restrict__ g,
                             int* __restrict__ hist) {
    __shared__ float2 buf[512];
    int r = blockIdx.x;
    int tid = threadIdx.x;                 // 256 threads
    if (r < 16) hist[r * 256 + tid] = 0;   // 16*256 = 4096 bins
    int i1 = (r < 128) ? r : r + 256;
    int k1 = (r < 128) ? r : r - 256;
    float a1 = TWO_PI_OVER_N * (float)k1;
    float ph1 = i0f_dev(4.0f * sqrtf(B_KB2 - a1 * a1));

    int k2 = tid - 128;                    // [-128, 128)
    int i2 = k2 & 511;
    float a2 = TWO_PI_OVER_N * (float)k2;
    float ph2 = i0f_dev(4.0f * sqrtf(B_KB2 - a2 * a2));
    float inv = 1.0f / (ph1 * ph2);
    if ((i1 + i2) & 1) inv = -inv;
    int fidx = (k1 + 128) * 256 + (k2 + 128);
    float2 v = make_float2(fr[fidx] * inv, fi[fidx] * inv);

    buf[tid] = make_float2(0.0f, 0.0f);
    buf[tid + 256] = make_float2(0.0f, 0.0f);
    __syncthreads();
    int ri = (int)(__brev((unsigned)i2) >> 23);   // 9-bit reversal
    buf[ri] = v;
    __syncthreads();

    #pragma unroll
    for (int s = 1; s <= 9; ++s) {
        int half = 1 << (s - 1);
        int pos = tid & (half - 1);
        int j1 = ((tid >> (s - 1)) << s) | pos;
        float ang = -PI_F * (float)pos / (float)half;
        float sw, cw;
        __sincosf(ang, &sw, &cw);
        float2 u = buf[j1];
        float2 w = buf[j1 + half];
        float wr = cw * w.x - sw * w.y;
        float wi = cw * w.y + sw * w.x;
        buf[j1]        = make_float2(u.x + wr, u.y + wi);
        buf[j1 + half] = make_float2(u.x - wr, u.y - wi);
        __syncthreads();
    }
    long base = (long)i1 * NCOL;
    for (int j = tid; j < 512; j += 256) g[base + j] = buf[j];
    if (tid < 8) g[base + 512 + tid] = buf[tid];   // duplicate cols for padding
}

// ---- Column FFT over the 256 nonzero rows only; REAL part to f32 grid. ----
__global__ void colfft_real(const float2* __restrict__ g,
                            float* __restrict__ gre) {
    __shared__ float2 buf[512];
    int c = blockIdx.x;                    // 0..519
    int tid = threadIdx.x;                 // 256 threads
    buf[tid] = make_float2(0.0f, 0.0f);
    buf[tid + 256] = make_float2(0.0f, 0.0f);
    __syncthreads();
    int r = (tid < 128) ? tid : tid + 256;           // nonzero rows
    int rr = (int)(__brev((unsigned)r) >> 23);       // 9-bit reversal
    buf[rr] = g[(long)r * NCOL + c];
    __syncthreads();
    #pragma unroll
    for (int s = 1; s <= 9; ++s) {
        int half = 1 << (s - 1);
        int pos = tid & (half - 1);
        int j1 = ((tid >> (s - 1)) << s) | pos;
        float ang = -PI_F * (float)pos / (float)half;
        float sw, cw;
        __sincosf(ang, &sw, &cw);
        float2 u = buf[j1];
        float2 w = buf[j1 + half];
        float wr = cw * w.x - sw * w.y;
        float wi = cw * w.y + sw * w.x;
        buf[j1]        = make_float2(u.x + wr, u.y + wi);
        buf[j1 + half] = make_float2(u.x - wr, u.y - wi);
        __syncthreads();
    }
    for (int j = tid; j < 512; j += 256) gre[(long)j * NCOL + c] = buf[j].x;
}

// ---- Counting sort of points by 8x8 grid tile ----
__global__ void hist_pts(const float2* __restrict__ x, int* __restrict__ hist) {
    int m = blockIdx.x * 256 + threadIdx.x;
    atomicAdd(&hist[bucket_of(x[m])], 1);
}

__global__ void scan_bins(const int* __restrict__ hist, int* __restrict__ cursor) {
    __shared__ int s[1024];
    int t = threadIdx.x;                   // 1024 threads, 4 bins each
    int h0 = hist[t*4], h1 = hist[t*4+1], h2 = hist[t*4+2], h3 = hist[t*4+3];
    int part = h0 + h1 + h2 + h3;
    s[t] = part;
    __syncthreads();
    for (int off = 1; off < 1024; off <<= 1) {
        int v = (t >= off) ? s[t - off] : 0;
        __syncthreads();
        s[t] += v;
        __syncthreads();
    }
    int run = s[t] - part;                 // exclusive prefix
    cursor[t*4]   = run; run += h0;
    cursor[t*4+1] = run; run += h1;
    cursor[t*4+2] = run; run += h2;
    cursor[t*4+3] = run;
}

__global__ void scatter_pts(const float2* __restrict__ x,
                            int* __restrict__ cursor,
                            float4* __restrict__ srec) {
    int m = blockIdx.x * 256 + threadIdx.x;
    float2 xv = x[m];
    int slot = atomicAdd(&cursor[bucket_of(xv)], 1);
    srec[slot] = make_float4(xv.x, xv.y, __int_as_float(m), 0.0f);
}

// ---- Gather over tile-sorted points: waves touch overlapping grid lines. ----
__global__ __launch_bounds__(256, 4)
void gather_sorted(const float4* __restrict__ srec,
                   const float* __restrict__ gre,
                   float* __restrict__ out) {
    int slot = blockIdx.x * 256 + threadIdx.x;
    float4 rec = srec[slot];
    float v1 = rec.x * 512.0f;
    float v2 = rec.y * 512.0f;
    int m = __float_as_int(rec.z);
    float c1 = ceilf(v1), c2 = ceilf(v2);
    int b1 = (int)c1 - 4, b2 = (int)c2 - 4;
    float f1 = c1 - v1, f2 = c2 - v2;

    float phi1[8], phi2[8];
    int rowb[8];
    #pragma unroll
    for (int w = 0; w < 8; ++w) {
        phi1[w] = phi_win(4.0f - (float)w - f1);
        phi2[w] = phi_win(4.0f - (float)w - f2);
        rowb[w] = ((b1 + w + 768) & 511) * NCOL;
    }
    int cb = (b2 + 768) & 511;

    float4 rA[8], rB[8];
    #pragma unroll
    for (int w = 0; w < 8; ++w) {
        const float4* p = reinterpret_cast<const float4*>(gre + rowb[w] + cb);
        rA[w] = p[0];
        rB[w] = p[1];
    }
    float acc = 0.0f;
    #pragma unroll
    for (int w = 0; w < 8; ++w) {
        acc += phi1[w] * (phi2[0]*rA[w].x + phi2[1]*rA[w].y +
                          phi2[2]*rA[w].z + phi2[3]*rA[w].w +
                          phi2[4]*rB[w].x + phi2[5]*rB[w].y +
                          phi2[6]*rB[w].z + phi2[7]*rB[w].w);
    }
    out[m] = acc;
}

// ================== fallback path (complex-capable, f32) ==================
__global__ void build_ghat(const float* __restrict__ fr,
                           const float* __restrict__ fi,
                           float2* __restrict__ g, int ldg) {
    int idx = blockIdx.x * 256 + threadIdx.x;
    int i1 = idx >> 9;
    int i2 = idx & 511;
    float2 val = make_float2(0.0f, 0.0f);
    int k1 = 0, k2 = 0;
    bool ok = true;
    if (i1 < 128) k1 = i1; else if (i1 >= 384) k1 = i1 - 512; else ok = false;
    if (ok) { if (i2 < 128) k2 = i2; else if (i2 >= 384) k2 = i2 - 512; else ok = false; }
    if (ok) {
        float a1 = TWO_PI_OVER_N * (float)k1;
        float a2 = TWO_PI_OVER_N * (float)k2;
        float ph1 = i0f_dev(4.0f * sqrtf(B_KB2 - a1*a1));
        float ph2 = i0f_dev(4.0f * sqrtf(B_KB2 - a2*a2));
        float inv = 1.0f / (ph1 * ph2);
        if ((i1 + i2) & 1) inv = -inv;
        int fidx = (k1 + 128) * 256 + (k2 + 128);
        val.x = fr[fidx] * inv;
        val.y = fi[fidx] * inv;
    }
    g[i1 * ldg + i2] = val;
}

__global__ void fft_lines(float2* __restrict__ g, int line_stride,
                          int elem_stride, int ndup) {
    __shared__ float2 buf[512];
    int line = blockIdx.x;
    int tid = threadIdx.x;
    long base = (long)line * line_stride;
    for (int j = tid; j < 512; j += 256) {
        int rj = (int)(__brev((unsigned)j) >> 23);
        buf[rj] = g[base + (long)j * elem_stride];
    }
    __syncthreads();
    #pragma unroll
    for (int s = 1; s <= 9; ++s) {
        int half = 1 << (s - 1);
        int pos = tid & (half - 1);
        int i1 = ((tid >> (s - 1)) << s) | pos;
        float ang = -PI_F * (float)pos / (float)half;
        float sw, cw;
        __sincosf(ang, &sw, &cw);
        float2 u = buf[i1];
        float2 v = buf[i1 + half];
        float wr = cw * v.x - sw * v.y;
        float wi = cw * v.y + sw * v.x;
        buf[i1]        = make_float2(u.x + wr, u.y + wi);
        buf[i1 + half] = make_float2(u.x - wr, u.y - wi);
        __syncthreads();
    }
    for (int j = tid; j < 512; j += 256) g[base + (long)j * elem_stride] = buf[j];
    for (int j = tid; j < ndup; j += 256) g[base + 512 + j] = buf[j];
}

template<int COMPLEX>
__global__ __launch_bounds__(256, 4)
void gather_pad(const float2* __restrict__ x,
                const float2* __restrict__ g,
                float* __restrict__ out) {
    int m = blockIdx.x * 256 + threadIdx.x;
    float2 xv = x[m];
    float v1 = xv.x * 512.0f;
    float v2 = xv.y * 512.0f;
    float c1 = ceilf(v1), c2 = ceilf(v2);
    int b1 = (int)c1 - 4, b2 = (int)c2 - 4;
    float f1 = c1 - v1, f2 = c2 - v2;

    float phi1[8], phi2[8];
    int rowb[8];
    #pragma unroll
    for (int w = 0; w < 8; ++w) {
        phi1[w] = phi_win(4.0f - (float)w - f1);
        phi2[w] = phi_win(4.0f - (float)w - f2);
        rowb[w] = ((b1 + w + 768) & 511) * NCOL;
    }
    int cb = (b2 + 768) & 511;

    float accx = 0.0f, accy = 0.0f;
    #pragma unroll
    for (int w1 = 0; w1 < 8; ++w1) {
        const float4* p = reinterpret_cast<const float4*>(g + rowb[w1] + cb);
        float4 va = p[0], vb = p[1], vc = p[2], vd = p[3];
        float p1 = phi1[w1];
        accx += p1 * (phi2[0]*va.x + phi2[1]*va.z + phi2[2]*vb.x + phi2[3]*vb.z +
                      phi2[4]*vc.x + phi2[5]*vc.z + phi2[6]*vd.x + phi2[7]*vd.z);
        if (COMPLEX)
            accy += p1 * (phi2[0]*va.y + phi2[1]*va.w + phi2[2]*vb.y + phi2[3]*vb.w +
                          phi2[4]*vc.y + phi2[5]*vc.w + phi2[6]*vd.y + phi2[7]*vd.w);
    }
    if (COMPLEX) ((float2*)out)[m] = make_float2(accx, accy);
    else out[m] = accx;
}

extern "C" void kernel_launch(void* const* d_in, const int* in_sizes, int n_in,
                              void* d_out, int out_size, void* d_ws, size_t ws_size,
                              hipStream_t stream) {
    const float* x  = (const float*)d_in[0];
    const float* fr = (const float*)d_in[1];
    const float* fi = (const float*)d_in[2];
    int cplx = (out_size >= 2 * NPTS) ? 1 : 0;

    size_t g_bytes    = (size_t)512 * NCOL * sizeof(float2);  // 2,129,920
    size_t gre_bytes  = (size_t)512 * NCOL * sizeof(float);   // 1,064,960
    size_t hist_bytes = (size_t)NBKT * sizeof(int);           // 16,384
    size_t srec_bytes = (size_t)NPTS * sizeof(float4);        // 4 MiB
    char* ws = (char*)d_ws;
    float2* g      = (float2*)ws;
    float*  gre    = (float*)(ws + g_bytes);
    int*    hist   = (int*)(ws + g_bytes + gre_bytes);
    int*    cursor = (int*)(ws + g_bytes + gre_bytes + hist_bytes);
    float4* srec   = (float4*)(ws + g_bytes + gre_bytes + 2 * hist_bytes);
    size_t need = g_bytes + gre_bytes + 2 * hist_bytes + srec_bytes;

    if (!cplx && ws_size >= need) {
        // Fast path: fused build+rowFFT (zeros hist), counting sort by tile,
        // zero-row-aware colFFT, locality-sorted gather.
        rowfft_build<<<256, 256, 0, stream>>>(fr, fi, g, hist);
        hist_pts<<<1024, 256, 0, stream>>>((const float2*)x, hist);
        scan_bins<<<1, 1024, 0, stream>>>(hist, cursor);
        scatter_pts<<<1024, 256, 0, stream>>>((const float2*)x, cursor, srec);
        colfft_real<<<NCOL, 256, 0, stream>>>(g, gre);
        gather_sorted<<<1024, 256, 0, stream>>>(srec, gre, (float*)d_out);
    } else if (ws_size >= g_bytes) {
        build_ghat<<<1024, 256, 0, stream>>>(fr, fi, g, NCOL);
        fft_lines<<<512, 256, 0, stream>>>(g, NCOL, 1, 8);
        fft_lines<<<NCOL, 256, 0, stream>>>(g, 1, NCOL, 0);
        if (cplx)
            gather_pad<1><<<1024, 256, 0, stream>>>((const float2*)x, g, (float*)d_out);
        else
            gather_pad<0><<<1024, 256, 0, stream>>>((const float2*)x, g, (float*)d_out);
    } else {
        build_ghat<<<1024, 256, 0, stream>>>(fr, fi, g, 512);
        fft_lines<<<512, 256, 0, stream>>>(g, 512, 1, 0);
        fft_lines<<<512, 256, 0, stream>>>(g, 1, 512, 0);
        if (cplx)
            gather_pad<1><<<1024, 256, 0, stream>>>((const float2*)x, g, (float*)d_out);
        else
            gather_pad<0><<<1024, 256, 0, stream>>>((const float2*)x, g, (float*)d_out);
    }
}

// Round 8
// 36.311 us; speedup vs baseline: 1.9157x; 1.9157x over previous
//
#include <hip/hip_runtime.h>
#include <math.h>

#define NPTS 262144
#define B_KB 4.71238898038469f      /* 1.5*pi */
#define B_KB2 22.2066099025f        /* B_KB^2 */
#define PI_F 3.14159265358979f
#define INV_2PI 0.15915494309f      /* 1/(2*pi) */
#define TWO_PI_OVER_N 0.01227184630309f /* 2*pi/512 */
#define NCOL 520                    /* padded complex row stride */
#define NCOLH 528                   /* padded f16 row stride (8B-aligned rows) */
#define PLANE (512 * NCOLH)         /* one parity plane, elements */
#define S_SCALE 1.37438953472e11f   /* 2^37: grid rescale into f16 range */
#define INV_S   7.27595761418e-12f  /* 2^-37 */

typedef _Float16 half8v __attribute__((ext_vector_type(8)));

__device__ __forceinline__ float i0f_dev(float x) {
    float ax = fabsf(x);
    if (ax < 3.75f) {
        float t = ax / 3.75f; t *= t;
        return 1.0f + t*(3.5156229f + t*(3.0899424f + t*(1.2067492f +
               t*(0.2659732f + t*(0.0360768f + t*0.0045813f)))));
    } else {
        float t = 3.75f / ax;
        float p = 0.39894228f + t*(0.01328592f + t*(0.00225319f + t*(-0.00157565f +
                  t*(0.00916281f + t*(-0.02057706f + t*(0.02635537f +
                  t*(-0.01647633f + t*0.00392377f)))))));
        return expf(ax) * p / sqrtf(ax);
    }
}

// Kaiser-Bessel window via raw v_exp/v_rcp: sinh(B*a)/(pi*a), a=sqrt(16-t^2)
__device__ __forceinline__ float phi_win(float t) {
    float s = 16.0f - t * t;
    if (s <= 0.0f) return 0.0f;
    float a = sqrtf(s);
    float ez = __expf(B_KB * a);
    return (ez - __builtin_amdgcn_rcpf(ez)) * INV_2PI * __builtin_amdgcn_rcpf(a);
}

// ---- Fused deconvolution + row FFT (rows with nonzero spectrum only). ----
// Scale S folded in so the f16 grid lands in normal range. Sign (-1)^(i1+i2)
// folded so the FFT output needs no ifftshift.
__global__ void rowfft_build(const float* __restrict__ fr,
                             const float* __restrict__ fi,
                             float2* __restrict__ g) {
    __shared__ float2 buf[512];
    int r = blockIdx.x;
    int i1 = (r < 128) ? r : r + 256;
    int k1 = (r < 128) ? r : r - 256;
    int tid = threadIdx.x;                 // 256 threads
    float a1 = TWO_PI_OVER_N * (float)k1;
    float ph1 = i0f_dev(4.0f * sqrtf(B_KB2 - a1 * a1));

    int k2 = tid - 128;                    // [-128, 128)
    int i2 = k2 & 511;
    float a2 = TWO_PI_OVER_N * (float)k2;
    float ph2 = i0f_dev(4.0f * sqrtf(B_KB2 - a2 * a2));
    float inv = S_SCALE / (ph1 * ph2);
    if ((i1 + i2) & 1) inv = -inv;
    int fidx = (k1 + 128) * 256 + (k2 + 128);
    float2 v = make_float2(fr[fidx] * inv, fi[fidx] * inv);

    buf[tid] = make_float2(0.0f, 0.0f);
    buf[tid + 256] = make_float2(0.0f, 0.0f);
    __syncthreads();
    int ri = (int)(__brev((unsigned)i2) >> 23);   // 9-bit reversal
    buf[ri] = v;
    __syncthreads();

    #pragma unroll
    for (int s = 1; s <= 9; ++s) {
        int half = 1 << (s - 1);
        int pos = tid & (half - 1);
        int j1 = ((tid >> (s - 1)) << s) | pos;
        float ang = -PI_F * (float)pos / (float)half;
        float sw, cw;
        __sincosf(ang, &sw, &cw);
        float2 u = buf[j1];
        float2 w = buf[j1 + half];
        float wr = cw * w.x - sw * w.y;
        float wi = cw * w.y + sw * w.x;
        buf[j1]        = make_float2(u.x + wr, u.y + wi);
        buf[j1 + half] = make_float2(u.x - wr, u.y - wi);
        __syncthreads();
    }
    long base = (long)i1 * NCOL;
    for (int j = tid; j < 512; j += 256) g[base + j] = buf[j];
    if (tid < 8) g[base + 512 + tid] = buf[tid];   // duplicate cols for padding
}

// ---- Column FFT over the 256 nonzero rows only; REAL part as f16, written
// TRANSPOSED (ghT[c][j]) so all global stores are lane-contiguous. ----
__global__ void colfft_f16T(const float2* __restrict__ g,
                            _Float16* __restrict__ ghT) {
    __shared__ float2 buf[512];
    int c = blockIdx.x;                    // 0..519
    int tid = threadIdx.x;                 // 256 threads
    buf[tid] = make_float2(0.0f, 0.0f);
    buf[tid + 256] = make_float2(0.0f, 0.0f);
    __syncthreads();
    int r = (tid < 128) ? tid : tid + 256;           // nonzero rows
    int rr = (int)(__brev((unsigned)r) >> 23);       // 9-bit reversal
    buf[rr] = g[(long)r * NCOL + c];
    __syncthreads();
    #pragma unroll
    for (int s = 1; s <= 9; ++s) {
        int half = 1 << (s - 1);
        int pos = tid & (half - 1);
        int j1 = ((tid >> (s - 1)) << s) | pos;
        float ang = -PI_F * (float)pos / (float)half;
        float sw, cw;
        __sincosf(ang, &sw, &cw);
        float2 u = buf[j1];
        float2 w = buf[j1 + half];
        float wr = cw * w.x - sw * w.y;
        float wi = cw * w.y + sw * w.x;
        buf[j1]        = make_float2(u.x + wr, u.y + wi);
        buf[j1 + half] = make_float2(u.x - wr, u.y - wi);
        __syncthreads();
    }
    long base = (long)c * 512;
    ghT[base + tid]       = (_Float16)buf[tid].x;        // coalesced
    ghT[base + tid + 256] = (_Float16)buf[tid + 256].x;  // coalesced
}

// ---- LDS-tiled transpose ghT[c][j] -> 4 parity planes gh[d][j][c-d].
// Coalesced reads AND coalesced writes. ----
__global__ void transpose_planes(const _Float16* __restrict__ ghT,
                                 _Float16* __restrict__ gh) {
    __shared__ _Float16 t[64][68];         // pad: 2-way LDS aliasing only
    int c0 = blockIdx.x * 64;              // 0..8 -> c tiles (last partial: 512..519)
    int j0 = blockIdx.y * 64;              // 0..7 -> j tiles
    int lx = threadIdx.x & 63;
    int ly = threadIdx.x >> 6;             // 0..3
    for (int r = 0; r < 64; r += 4) {
        int c = c0 + ly + r;
        if (c < 520) t[ly + r][lx] = ghT[(long)c * 512 + j0 + lx];
    }
    __syncthreads();
    int c = c0 + lx;
    bool cok = (c < 520);
    for (int r = 0; r < 64; r += 4) {
        int j = j0 + ly + r;
        _Float16 v = t[lx][ly + r];
        long rb = (long)j * NCOLH;
        #pragma unroll
        for (int d = 0; d < 4; ++d) {
            if (cok && c >= d) gh[d * PLANE + rb + (c - d)] = v;  // coalesced
        }
    }
}

// ---- Gather from f16 parity planes: 8 rows x one dwordx4 (8 halves). ----
__global__ __launch_bounds__(256, 4)
void gather_f16(const float2* __restrict__ x,
                const _Float16* __restrict__ gh,
                float* __restrict__ out) {
    int m = blockIdx.x * 256 + threadIdx.x;
    float2 xv = x[m];
    float v1 = xv.x * 512.0f;
    float v2 = xv.y * 512.0f;
    float c1 = ceilf(v1), c2 = ceilf(v2);
    int b1 = (int)c1 - 4, b2 = (int)c2 - 4;
    float f1 = c1 - v1, f2 = c2 - v2;

    float phi1[8], phi2[8];
    int rowb[8];
    #pragma unroll
    for (int w = 0; w < 8; ++w) {
        phi1[w] = phi_win(4.0f - (float)w - f1) * INV_S;
        phi2[w] = phi_win(4.0f - (float)w - f2);
        rowb[w] = ((b1 + w + 768) & 511) * NCOLH;
    }
    int cb = (b2 + 768) & 511;
    int d  = cb & 3;
    const _Float16* base = gh + d * PLANE + (cb - d);

    half8v rv[8];
    #pragma unroll
    for (int w = 0; w < 8; ++w) {
        rv[w] = *reinterpret_cast<const half8v*>(base + rowb[w]);
    }
    float acc = 0.0f;
    #pragma unroll
    for (int w = 0; w < 8; ++w) {
        float rs = phi2[0]*(float)rv[w][0] + phi2[1]*(float)rv[w][1] +
                   phi2[2]*(float)rv[w][2] + phi2[3]*(float)rv[w][3] +
                   phi2[4]*(float)rv[w][4] + phi2[5]*(float)rv[w][5] +
                   phi2[6]*(float)rv[w][6] + phi2[7]*(float)rv[w][7];
        acc += phi1[w] * rs;
    }
    out[m] = acc;
}

// ================== fallback path (complex-capable, f32) ==================
__global__ void build_ghat(const float* __restrict__ fr,
                           const float* __restrict__ fi,
                           float2* __restrict__ g, int ldg) {
    int idx = blockIdx.x * 256 + threadIdx.x;
    int i1 = idx >> 9;
    int i2 = idx & 511;
    float2 val = make_float2(0.0f, 0.0f);
    int k1 = 0, k2 = 0;
    bool ok = true;
    if (i1 < 128) k1 = i1; else if (i1 >= 384) k1 = i1 - 512; else ok = false;
    if (ok) { if (i2 < 128) k2 = i2; else if (i2 >= 384) k2 = i2 - 512; else ok = false; }
    if (ok) {
        float a1 = TWO_PI_OVER_N * (float)k1;
        float a2 = TWO_PI_OVER_N * (float)k2;
        float ph1 = i0f_dev(4.0f * sqrtf(B_KB2 - a1*a1));
        float ph2 = i0f_dev(4.0f * sqrtf(B_KB2 - a2*a2));
        float inv = 1.0f / (ph1 * ph2);
        if ((i1 + i2) & 1) inv = -inv;
        int fidx = (k1 + 128) * 256 + (k2 + 128);
        val.x = fr[fidx] * inv;
        val.y = fi[fidx] * inv;
    }
    g[i1 * ldg + i2] = val;
}

__global__ void fft_lines(float2* __restrict__ g, int line_stride,
                          int elem_stride, int ndup) {
    __shared__ float2 buf[512];
    int line = blockIdx.x;
    int tid = threadIdx.x;
    long base = (long)line * line_stride;
    for (int j = tid; j < 512; j += 256) {
        int rj = (int)(__brev((unsigned)j) >> 23);
        buf[rj] = g[base + (long)j * elem_stride];
    }
    __syncthreads();
    #pragma unroll
    for (int s = 1; s <= 9; ++s) {
        int half = 1 << (s - 1);
        int pos = tid & (half - 1);
        int i1 = ((tid >> (s - 1)) << s) | pos;
        float ang = -PI_F * (float)pos / (float)half;
        float sw, cw;
        __sincosf(ang, &sw, &cw);
        float2 u = buf[i1];
        float2 v = buf[i1 + half];
        float wr = cw * v.x - sw * v.y;
        float wi = cw * v.y + sw * v.x;
        buf[i1]        = make_float2(u.x + wr, u.y + wi);
        buf[i1 + half] = make_float2(u.x - wr, u.y - wi);
        __syncthreads();
    }
    for (int j = tid; j < 512; j += 256) g[base + (long)j * elem_stride] = buf[j];
    for (int j = tid; j < ndup; j += 256) g[base + 512 + j] = buf[j];
}

template<int COMPLEX>
__global__ __launch_bounds__(256, 4)
void gather_pad(const float2* __restrict__ x,
                const float2* __restrict__ g,
                float* __restrict__ out) {
    int m = blockIdx.x * 256 + threadIdx.x;
    float2 xv = x[m];
    float v1 = xv.x * 512.0f;
    float v2 = xv.y * 512.0f;
    float c1 = ceilf(v1), c2 = ceilf(v2);
    int b1 = (int)c1 - 4, b2 = (int)c2 - 4;
    float f1 = c1 - v1, f2 = c2 - v2;

    float phi1[8], phi2[8];
    int rowb[8];
    #pragma unroll
    for (int w = 0; w < 8; ++w) {
        phi1[w] = phi_win(4.0f - (float)w - f1);
        phi2[w] = phi_win(4.0f - (float)w - f2);
        rowb[w] = ((b1 + w + 768) & 511) * NCOL;
    }
    int cb = (b2 + 768) & 511;

    float accx = 0.0f, accy = 0.0f;
    #pragma unroll
    for (int w1 = 0; w1 < 8; ++w1) {
        const float4* p = reinterpret_cast<const float4*>(g + rowb[w1] + cb);
        float4 va = p[0], vb = p[1], vc = p[2], vd = p[3];
        float p1 = phi1[w1];
        accx += p1 * (phi2[0]*va.x + phi2[1]*va.z + phi2[2]*vb.x + phi2[3]*vb.z +
                      phi2[4]*vc.x + phi2[5]*vc.z + phi2[6]*vd.x + phi2[7]*vd.z);
        if (COMPLEX)
            accy += p1 * (phi2[0]*va.y + phi2[1]*va.w + phi2[2]*vb.y + phi2[3]*vb.w +
                          phi2[4]*vc.y + phi2[5]*vc.w + phi2[6]*vd.y + phi2[7]*vd.w);
    }
    if (COMPLEX) ((float2*)out)[m] = make_float2(accx, accy);
    else out[m] = accx;
}

extern "C" void kernel_launch(void* const* d_in, const int* in_sizes, int n_in,
                              void* d_out, int out_size, void* d_ws, size_t ws_size,
                              hipStream_t stream) {
    const float* x  = (const float*)d_in[0];
    const float* fr = (const float*)d_in[1];
    const float* fi = (const float*)d_in[2];
    int cplx = (out_size >= 2 * NPTS) ? 1 : 0;

    size_t g_bytes   = (size_t)512 * NCOL * sizeof(float2);    // 2,129,920
    size_t ghT_bytes = (size_t)520 * 512 * sizeof(_Float16);   //   532,480
    size_t gh_bytes  = (size_t)4 * PLANE * sizeof(_Float16);   // 2,162,688
    char* ws = (char*)d_ws;
    float2*   g   = (float2*)ws;
    _Float16* ghT = (_Float16*)(ws + g_bytes);
    _Float16* gh  = (_Float16*)(ws + g_bytes + ghT_bytes);
    size_t need = g_bytes + ghT_bytes + gh_bytes;

    if (!cplx && ws_size >= need) {
        // Fast path: fused build+rowFFT, coalesced-store colFFT (transposed
        // f16), LDS-tiled plane transpose, 8-load gather.
        rowfft_build<<<256, 256, 0, stream>>>(fr, fi, g);
        colfft_f16T<<<NCOL, 256, 0, stream>>>(g, ghT);
        transpose_planes<<<dim3(9, 8), 256, 0, stream>>>(ghT, gh);
        gather_f16<<<1024, 256, 0, stream>>>((const float2*)x, gh, (float*)d_out);
    } else if (ws_size >= g_bytes) {
        build_ghat<<<1024, 256, 0, stream>>>(fr, fi, g, NCOL);
        fft_lines<<<512, 256, 0, stream>>>(g, NCOL, 1, 8);
        fft_lines<<<NCOL, 256, 0, stream>>>(g, 1, NCOL, 0);
        if (cplx)
            gather_pad<1><<<1024, 256, 0, stream>>>((const float2*)x, g, (float*)d_out);
        else
            gather_pad<0><<<1024, 256, 0, stream>>>((const float2*)x, g, (float*)d_out);
    } else {
        build_ghat<<<1024, 256, 0, stream>>>(fr, fi, g, 512);
        fft_lines<<<512, 256, 0, stream>>>(g, 512, 1, 0);
        fft_lines<<<512, 256, 0, stream>>>(g, 1, 512, 0);
        if (cplx)
            gather_pad<1><<<1024, 256, 0, stream>>>((const float2*)x, g, (float*)d_out);
        else
            gather_pad<0><<<1024, 256, 0, stream>>>((const float2*)x, g, (float*)d_out);
    }
}